// Round 1
// baseline (79.711 us; speedup 1.0000x reference)
//
#include <hip/hip_runtime.h>

#define BINS 10

// Per-element processing: update per-thread register histograms.
// Arrays passed by reference-to-array so all indexing stays compile-time
// (statically unrolled predicated adds -> registers, no scratch).
__device__ __forceinline__ void ghm_accum(float x, float tt,
                                          float (&s)[BINS], int (&c)[BINS]) {
    float em = __expf(-fabsf(x));                       // e^{-|x|}
    float sig = (x >= 0.f) ? (1.f / (1.f + em)) : (em / (1.f + em));
    float g = fabsf(sig - tt);                          // in (0,1)
    int idx = 0;
#pragma unroll
    for (int b = 1; b < BINS; ++b)
        idx += (g >= ((float)b / (float)BINS)) ? 1 : 0; // == searchsorted(right)-1
    float bce = fmaxf(x, 0.f) - x * tt + __logf(1.f + em);
#pragma unroll
    for (int b = 0; b < BINS; ++b) {
        bool m = (idx == b);
        s[b] += m ? bce : 0.f;
        c[b] += m ? 1 : 0;
    }
}

__global__ __launch_bounds__(256) void ghm_pass1(
    const float* __restrict__ pred, const float* __restrict__ tgt,
    long long n, int nb,
    float* __restrict__ bsum, int* __restrict__ bcnt)
{
    float s[BINS];
    int   c[BINS];
#pragma unroll
    for (int b = 0; b < BINS; ++b) { s[b] = 0.f; c[b] = 0; }

    const long long n4 = n >> 2;
    const float4* p4 = (const float4*)pred;
    const float4* t4 = (const float4*)tgt;
    const long long stride = (long long)nb * 256;

    for (long long i = (long long)blockIdx.x * 256 + threadIdx.x; i < n4; i += stride) {
        float4 p = p4[i];
        float4 t = t4[i];
        ghm_accum(p.x, t.x, s, c);
        ghm_accum(p.y, t.y, s, c);
        ghm_accum(p.z, t.z, s, c);
        ghm_accum(p.w, t.w, s, c);
    }

    // tail (n not divisible by 4) — handled by block 0
    const long long tail0 = n4 << 2;
    if (blockIdx.x == 0 && (long long)threadIdx.x < (n - tail0)) {
        long long i = tail0 + threadIdx.x;
        ghm_accum(pred[i], tgt[i], s, c);
    }

    // block reduce: wave shuffle, then cross-wave via LDS (deterministic)
    __shared__ float ls[4][BINS];
    __shared__ int   lc[4][BINS];
    const int lane = threadIdx.x & 63;
    const int wave = threadIdx.x >> 6;
#pragma unroll
    for (int b = 0; b < BINS; ++b) {
        float v = s[b];
        int   k = c[b];
        for (int off = 32; off; off >>= 1) {
            v += __shfl_down(v, off);
            k += __shfl_down(k, off);
        }
        if (lane == 0) { ls[wave][b] = v; lc[wave][b] = k; }
    }
    __syncthreads();
    if (threadIdx.x < BINS) {
        int b = threadIdx.x;
        float v = ls[0][b] + ls[1][b] + ls[2][b] + ls[3][b];
        int   k = lc[0][b] + lc[1][b] + lc[2][b] + lc[3][b];
        // bin-major layout so pass2 reads each bin's partials coalesced
        bsum[(long long)b * nb + blockIdx.x] = v;
        bcnt[(long long)b * nb + blockIdx.x] = k;
    }
}

__global__ __launch_bounds__(256) void ghm_pass2(
    const float* __restrict__ bsum, const int* __restrict__ bcnt,
    int nb, float* __restrict__ out)
{
    __shared__ double    ssum[BINS];
    __shared__ long long scnt[BINS];
    const int tid  = threadIdx.x;
    const int lane = tid & 63;
    const int wave = tid >> 6;

    // each wave reduces bins wave, wave+4, wave+8 (deterministic tree)
    for (int b = wave; b < BINS; b += 4) {
        double    acc = 0.0;
        long long cc  = 0;
        for (int i = lane; i < nb; i += 64) {
            acc += (double)bsum[(long long)b * nb + i];
            cc  += (long long)bcnt[(long long)b * nb + i];
        }
        for (int off = 32; off; off >>= 1) {
            acc += __shfl_down(acc, off);
            cc  += __shfl_down(cc, off);
        }
        if (lane == 0) { ssum[b] = acc; scnt[b] = cc; }
    }
    __syncthreads();

    if (tid == 0) {
        int n = 0;
#pragma unroll
        for (int b = 0; b < BINS; ++b) n += (scnt[b] > 0) ? 1 : 0;
        double loss = 0.0;
        if (n > 0) {
#pragma unroll
            for (int b = 0; b < BINS; ++b)
                if (scnt[b] > 0)
                    loss += ssum[b] / ((double)scnt[b] * (double)n);
        }
        out[0] = (float)loss;
    }
}

extern "C" void kernel_launch(void* const* d_in, const int* in_sizes, int n_in,
                              void* d_out, int out_size, void* d_ws, size_t ws_size,
                              hipStream_t stream) {
    const float* pred = (const float*)d_in[0];
    const float* tgt  = (const float*)d_in[1];
    float* out = (float*)d_out;
    const long long n = (long long)in_sizes[0];

    int nb = 2048;
    const size_t per_block = (size_t)BINS * (sizeof(float) + sizeof(int)); // 80 B
    if ((size_t)nb * per_block > ws_size) nb = (int)(ws_size / per_block);
    if (nb < 1) nb = 1;

    float* bsum = (float*)d_ws;
    int*   bcnt = (int*)((char*)d_ws + (size_t)nb * BINS * sizeof(float));

    ghm_pass1<<<nb, 256, 0, stream>>>(pred, tgt, n, nb, bsum, bcnt);
    ghm_pass2<<<1, 256, 0, stream>>>(bsum, bcnt, nb, out);
}